// Round 2
// baseline (822.933 us; speedup 1.0000x reference)
//
#include <hip/hip_runtime.h>

typedef __bf16 bf16x8 __attribute__((ext_vector_type(8)));
typedef float f32x4 __attribute__((ext_vector_type(4)));

#define B_ 4
#define H_ 16
#define T_ 2048
#define E_ 2048
#define D_ 128

// async global->LDS, 16B per lane; dest = wave-uniform base + lane*16
#define GLDS(g, l)                                                   \
  __builtin_amdgcn_global_load_lds(                                  \
      (const __attribute__((address_space(1))) void*)(g),            \
      (__attribute__((address_space(3))) void*)(l), 16, 0, 0)

// raw barrier: rendezvous only, NO implicit vmcnt/lgkm drain.
// (asm("s_barrier":::"memory") is mayLoad/mayStore -> SIInsertWaitcnts drains
// vmcnt before it, which nullified the counted-vmcnt pipeline in round 0.)
#define BAR() __builtin_amdgcn_s_barrier()

#define MFMA16(a, b, c) __builtin_amdgcn_mfma_f32_16x16x32_bf16((a), (b), (c), 0, 0, 0)

// ---------------- f32 -> bf16 elementwise convert ---------------------------
__global__ __launch_bounds__(256) void cvt_f32_bf16(const float* __restrict__ in,
                                                    __bf16* __restrict__ out) {
  size_t i = ((size_t)blockIdx.x * 256 + threadIdx.x) * 8;
  float4 a = *(const float4*)(in + i);
  float4 b = *(const float4*)(in + i + 4);
  bf16x8 v;
  v[0] = (__bf16)a.x; v[1] = (__bf16)a.y; v[2] = (__bf16)a.z; v[3] = (__bf16)a.w;
  v[4] = (__bf16)b.x; v[5] = (__bf16)b.y; v[6] = (__bf16)b.z; v[7] = (__bf16)b.w;
  *(bf16x8*)(out + i) = v;
}

// ------- 2048x2048 transpose + f32->bf16 (for weight B^T layout) ------------
__global__ __launch_bounds__(256) void transpose_w(const float* __restrict__ W,
                                                   __bf16* __restrict__ Wt) {
  __shared__ float tile[32][33];
  int bx = blockIdx.x & 63, by = blockIdx.x >> 6;
  int tx = threadIdx.x & 31, ty = threadIdx.x >> 5;
#pragma unroll
  for (int i = 0; i < 4; i++)
    tile[ty + i * 8][tx] = W[(size_t)(by * 32 + ty + i * 8) * 2048 + bx * 32 + tx];
  __syncthreads();
#pragma unroll
  for (int i = 0; i < 4; i++)
    Wt[(size_t)(bx * 32 + ty + i * 8) * 2048 + by * 32 + tx] =
        (__bf16)tile[tx][ty + i * 8];
}

// ---- bf16 GEMM: C[M,N] = A[M,K] @ Bt[N,K]^T ------------------------------
// 256x256 tile, BK=64, 8 waves (2M x 4N), 128 KiB LDS double-buffer.
// 8-phase schedule (4 phases per K-tile), counted vmcnt(6) — loads stay in
// flight across raw s_barriers; no vmcnt(0) drain in steady state (T3+T4).
// Stage lead: during K-tile T's 4 phases we stage A1(T+1) [ph0, other buf],
// B0(T+2) [ph2], A0(T+2)+B1(T+2) [ph3] — each overwrite lands >=1 barrier
// after the last ds_read of that slot (A halves last read ph2, B halves ph1).
// vmcnt(6) at end-of-ph3 == 3 newest half-tiles (K-tile T+2) outstanding,
// guarantees all of K-tile T+1 resident.
// LDS layout: [256][64] bf16, 16B-chunk XOR swizzle phys = logical ^ (row&7),
// pre-swizzled GLDS source; banks depend only on chunk -> conflict-free b128.
template <typename TOut>
__global__ __launch_bounds__(512, 2)
void gemm256(const __bf16* __restrict__ A, const __bf16* __restrict__ Bt,
             TOut* __restrict__ C, int N, int K) {
  __shared__ alignas(16) __bf16 As[2][256 * 64];
  __shared__ alignas(16) __bf16 Bs[2][256 * 64];

  // XCD-aware bijective swizzle (gridDim multiple of 8): each XCD gets a
  // contiguous chunk -> A-panel reuse lands in its private L2.
  const int nwg = gridDim.x;
  const int wg = (blockIdx.x & 7) * (nwg >> 3) + (blockIdx.x >> 3);
  const int ntn = N >> 8;
  const int tm = wg / ntn, tn = wg % ntn;

  const int tid = threadIdx.x;
  const int wave = tid >> 6, lane = tid & 63;
  const int quad = lane >> 4, l16 = lane & 15;
  const int wm = wave >> 2, wn = wave & 3;

  // staging source (pre-swizzled chunk so linear GLDS dest == swizzled layout)
  const int srow = wave * 8 + (lane >> 3);
  const int scol = (((lane & 7) ^ ((lane >> 3) & 7)) << 3);
  const __bf16* gA = A + (size_t)(tm * 256 + srow) * K + scol;
  const __bf16* gB = Bt + (size_t)(tn * 256 + srow) * K + scol;
  const int sdst = wave * 512;  // wave*8 rows * 64 bf16

#define STAGE_A(dbuf, h, U)                                                    \
  do {                                                                         \
    GLDS(gA + (size_t)((h)*128) * K + (size_t)(U)*64,                          \
         &As[dbuf][(h)*128 * 64 + sdst]);                                      \
    GLDS(gA + (size_t)((h)*128 + 64) * K + (size_t)(U)*64,                     \
         &As[dbuf][((h)*128 + 64) * 64 + sdst]);                               \
  } while (0)
#define STAGE_B(dbuf, h, U)                                                    \
  do {                                                                         \
    GLDS(gB + (size_t)((h)*128) * K + (size_t)(U)*64,                          \
         &Bs[dbuf][(h)*128 * 64 + sdst]);                                      \
    GLDS(gB + (size_t)((h)*128 + 64) * K + (size_t)(U)*64,                     \
         &Bs[dbuf][((h)*128 + 64) * 64 + sdst]);                               \
  } while (0)

  const int NT = K >> 6;  // K-tiles of 64 (NT >= 2 assumed; here K=2048)

  // frag chunk offsets (bf16 units): chunk(ks) = ((ks<<2)|quad) ^ (row&7),
  // row&7 == l16&7 for all frag rows (bases are multiples of 16).
  const int c0 = ((quad ^ (l16 & 7)) << 3);
  const int c1 = (((quad ^ (l16 & 7)) ^ 4) << 3);

  const f32x4 z4 = {0.f, 0.f, 0.f, 0.f};
  f32x4 acc[8][4];
#pragma unroll
  for (int m = 0; m < 8; m++)
#pragma unroll
    for (int n = 0; n < 4; n++) acc[m][n] = z4;

  bf16x8 a[4][2], b[4][2];

  // -------- prologue: K-tile 0 fully + 3 newest half-tiles of K-tile 1 -----
  STAGE_A(0, 0, 0);
  STAGE_B(0, 0, 0);
  STAGE_B(0, 1, 0);
  STAGE_A(0, 1, 0);
  STAGE_B(1, 0, 1);
  STAGE_A(1, 0, 1);
  STAGE_B(1, 1, 1);
  asm volatile("s_waitcnt vmcnt(6)");  // K-tile 0 resident (counted, no drain)
  BAR();

  for (int T = 0; T < NT; ++T) {
    const int d = T & 1;
    const __bf16* Adb = &As[d][0];
    const __bf16* Bdb = &Bs[d][0];
    const bool s1 = (T + 1 < NT), s2 = (T + 2 < NT);

    // ---- phase 0: read A m0-3 + B n0-1 (12 ds_read_b128); stage A1(T+1)
#pragma unroll
    for (int m = 0; m < 4; m++) {
      const __bf16* p = &Adb[(wm * 128 + m * 16 + l16) * 64];
      a[m][0] = *(const bf16x8*)(p + c0);
      a[m][1] = *(const bf16x8*)(p + c1);
    }
#pragma unroll
    for (int n = 0; n < 2; n++) {
      const __bf16* p = &Bdb[(wn * 64 + n * 16 + l16) * 64];
      b[n][0] = *(const bf16x8*)(p + c0);
      b[n][1] = *(const bf16x8*)(p + c1);
    }
    if (s1) STAGE_A(d ^ 1, 1, T + 1);
    BAR();
    asm volatile("s_waitcnt lgkmcnt(0)");
    __builtin_amdgcn_s_setprio(1);
#pragma unroll
    for (int m = 0; m < 4; m++)
#pragma unroll
      for (int n = 0; n < 2; n++) {
        acc[m][n] = MFMA16(a[m][0], b[n][0], acc[m][n]);
        acc[m][n] = MFMA16(a[m][1], b[n][1], acc[m][n]);
      }
    __builtin_amdgcn_s_setprio(0);
    BAR();

    // ---- phase 1: read B n2-3
#pragma unroll
    for (int n = 2; n < 4; n++) {
      const __bf16* p = &Bdb[(wn * 64 + n * 16 + l16) * 64];
      b[n][0] = *(const bf16x8*)(p + c0);
      b[n][1] = *(const bf16x8*)(p + c1);
    }
    BAR();
    asm volatile("s_waitcnt lgkmcnt(0)");
    __builtin_amdgcn_s_setprio(1);
#pragma unroll
    for (int m = 0; m < 4; m++)
#pragma unroll
      for (int n = 2; n < 4; n++) {
        acc[m][n] = MFMA16(a[m][0], b[n][0], acc[m][n]);
        acc[m][n] = MFMA16(a[m][1], b[n][1], acc[m][n]);
      }
    __builtin_amdgcn_s_setprio(0);
    BAR();

    // ---- phase 2: read A m4-7 (overwrite a[] regs); stage B0(T+2)
#pragma unroll
    for (int m = 0; m < 4; m++) {
      const __bf16* p = &Adb[(wm * 128 + (m + 4) * 16 + l16) * 64];
      a[m][0] = *(const bf16x8*)(p + c0);
      a[m][1] = *(const bf16x8*)(p + c1);
    }
    if (s2) STAGE_B(d, 0, T + 2);
    BAR();
    asm volatile("s_waitcnt lgkmcnt(0)");
    __builtin_amdgcn_s_setprio(1);
#pragma unroll
    for (int m = 0; m < 4; m++)
#pragma unroll
      for (int n = 2; n < 4; n++) {
        acc[m + 4][n] = MFMA16(a[m][0], b[n][0], acc[m + 4][n]);
        acc[m + 4][n] = MFMA16(a[m][1], b[n][1], acc[m + 4][n]);
      }
    __builtin_amdgcn_s_setprio(0);
    BAR();

    // ---- phase 3: no reads (reuse A m4-7 + B n0-1); stage A0(T+2)+B1(T+2)
    if (s2) {
      STAGE_A(d, 0, T + 2);
      STAGE_B(d, 1, T + 2);
    }
    BAR();
    __builtin_amdgcn_s_setprio(1);
#pragma unroll
    for (int m = 0; m < 4; m++)
#pragma unroll
      for (int n = 0; n < 2; n++) {
        acc[m + 4][n] = MFMA16(a[m][0], b[n][0], acc[m + 4][n]);
        acc[m + 4][n] = MFMA16(a[m][1], b[n][1], acc[m + 4][n]);
      }
    __builtin_amdgcn_s_setprio(0);
    // counted wait: 3 newest half-tiles (K-tile T+2) may stay in flight;
    // everything through A1(T+1) complete.  Tail: drain once.
    if (s2)
      asm volatile("s_waitcnt vmcnt(6)");
    else
      asm volatile("s_waitcnt vmcnt(0)");
    BAR();
  }

  // -------- epilogue: C[16x16 frag layout col=l16, row=quad*4+e] ----------
  const size_t rbase = (size_t)tm * 256 + wm * 128 + quad * 4;
  const int cbase = tn * 256 + wn * 64 + l16;
#pragma unroll
  for (int m = 0; m < 8; m++)
#pragma unroll
    for (int n = 0; n < 4; n++)
#pragma unroll
      for (int e = 0; e < 4; e++)
        C[(rbase + m * 16 + e) * N + cbase + n * 16] = (TOut)acc[m][n][e];
#undef STAGE_A
#undef STAGE_B
}

// ------------- RoPE + relayout [B*T, H*D] -> [B,H,T,D] ----------------------
// `scale` folds 1/sqrt(D)*log2(e) into Q so QK^T lands in the exp2 domain.
__global__ __launch_bounds__(256) void rope_relayout(const __bf16* __restrict__ raw,
                                                     const int* __restrict__ pos,
                                                     __bf16* __restrict__ out,
                                                     float scale) {
  int row = blockIdx.x;  // b*T + t
  int b = row >> 11, t = row & 2047;
  float p = (float)pos[row];
  for (int i = threadIdx.x; i < 1024; i += 256) {
    int h = i >> 6, d = i & 63;
    float inv = exp2f((float)d * -0.2076205059304601f);
    float ang = p * inv;
    float c = cosf(ang) * scale, s = sinf(ang) * scale;
    float q1 = (float)raw[(size_t)row * 2048 + h * 128 + d];
    float q2 = (float)raw[(size_t)row * 2048 + h * 128 + d + 64];
    size_t o = ((size_t)(b * 16 + h) * 2048 + t) * 128 + d;
    out[o] = (__bf16)(q1 * c - q2 * s);
    out[o + 64] = (__bf16)(q2 * c + q1 * s);
  }
}

// ------------- V relayout [B*T, H*D] -> Vt [B,H,D,T] ------------------------
__global__ __launch_bounds__(256) void vtrans(const __bf16* __restrict__ Vraw,
                                              __bf16* __restrict__ Vt) {
  __shared__ __bf16 tile[32][33];
  int dt = blockIdx.x & 3, tt = (blockIdx.x >> 2) & 63, bh = blockIdx.x >> 8;
  int b = bh >> 4, h = bh & 15;
  int tx = threadIdx.x & 31, ty = threadIdx.x >> 5;
#pragma unroll
  for (int i = 0; i < 4; i++) {
    int t = tt * 32 + ty + i * 8;
    tile[ty + i * 8][tx] = Vraw[(size_t)(b * T_ + t) * 2048 + h * 128 + dt * 32 + tx];
  }
  __syncthreads();
#pragma unroll
  for (int i = 0; i < 4; i++) {
    int d = dt * 32 + ty + i * 8;
    Vt[((size_t)bh * 128 + d) * T_ + tt * 32 + tx] = tile[tx][ty + i * 8];
  }
}

// ---- flash attention: 128 q/block, 32 q/wave (2 subtiles), 64-key tiles ----
// launch_bounds (256,3): LDS 52224*3 = 156672 <= 160 KiB -> 3 blocks/CU.
__global__ __launch_bounds__(256, 3)
void attn(const __bf16* __restrict__ Q, const __bf16* __restrict__ K,
          const __bf16* __restrict__ Vt, const int* __restrict__ mask,
          __bf16* __restrict__ Y) {
  __shared__ alignas(16) __bf16 Ks[64][136];   // [key][d], +8 pad
  __shared__ alignas(16) __bf16 Vs[128][72];   // [d][key], +8 pad
  __shared__ alignas(16) __bf16 Ps[4][32][64]; // per-wave P, XOR-16 swizzled cols

  const int qt = blockIdx.x & 15;  // T_/128 q-tiles
  const int bh = blockIdx.x >> 4;
  const int b = bh >> 4;
  const __bf16* Qb = Q + (size_t)bh * T_ * 128;
  const __bf16* Kb = K + (size_t)bh * T_ * 128;
  const __bf16* Vb = Vt + (size_t)bh * 128 * T_;
  const int* mb = mask + (size_t)b * T_;

  const int tid = threadIdx.x, wave = tid >> 6, lane = tid & 63;
  const int quad = lane >> 4, l16 = lane & 15;

  // Q fragments for 2 q-subtiles: A-layout A[m=l16][k=quad*8+j]
  bf16x8 qf[2][4];
  {
    int qrow = qt * 128 + wave * 32 + l16;
#pragma unroll
    for (int sub = 0; sub < 2; sub++)
#pragma unroll
      for (int kc = 0; kc < 4; kc++)
        qf[sub][kc] =
            *(const bf16x8*)(Qb + (size_t)(qrow + sub * 16) * 128 + kc * 32 + quad * 8);
  }

  const f32x4 z4 = {0.f, 0.f, 0.f, 0.f};
  f32x4 o0[8], o1[8];
#pragma unroll
  for (int n = 0; n < 8; n++) { o0[n] = z4; o1[n] = z4; }
  float lacc0[4] = {0.f, 0.f, 0.f, 0.f};
  float lacc1[4] = {0.f, 0.f, 0.f, 0.f};

  for (int t0 = 0; t0 < T_; t0 += 64) {
    __syncthreads();
#pragma unroll
    for (int rr = 0; rr < 4; rr++) {
      int idx = rr * 256 + tid;
      *(uint4*)&Ks[idx >> 4][(idx & 15) << 3] =
          *(const uint4*)(Kb + (size_t)(t0 + (idx >> 4)) * 128 + ((idx & 15) << 3));
      *(uint4*)&Vs[idx >> 3][(idx & 7) << 3] =
          *(const uint4*)(Vb + (size_t)(idx >> 3) * T_ + t0 + ((idx & 7) << 3));
    }
    __syncthreads();

    // S = Q K^T for both q-subtiles, sharing every kf read (exp2 domain)
    f32x4 s0[4], s1[4];
#pragma unroll
    for (int c = 0; c < 4; c++) { s0[c] = z4; s1[c] = z4; }
#pragma unroll
    for (int c = 0; c < 4; c++)
#pragma unroll
      for (int kc = 0; kc < 4; kc++) {
        bf16x8 kf = *(const bf16x8*)&Ks[c * 16 + l16][kc * 32 + quad * 8];
        s0[c] = __builtin_amdgcn_mfma_f32_16x16x32_bf16(qf[0][kc], kf, s0[c], 0, 0, 0);
        s1[c] = __builtin_amdgcn_mfma_f32_16x16x32_bf16(qf[1][kc], kf, s1[c], 0, 0, 0);
      }

    int mk[4];
#pragma unroll
    for (int c = 0; c < 4; c++) mk[c] = mb[t0 + c * 16 + l16];

#pragma unroll
    for (int c = 0; c < 4; c++) {
      int pcol = (c * 16 + l16) ^ (quad << 4);  // swizzle keyed on (row>>2)&3==quad
#pragma unroll
      for (int e = 0; e < 4; e++) {
        float v0 = __builtin_amdgcn_exp2f(s0[c][e]);
        float v1 = __builtin_amdgcn_exp2f(s1[c][e]);
        v0 = mk[c] ? 0.f : v0;   // exact: ref exp(finfo.min - m) == 0
        v1 = mk[c] ? 0.f : v1;
        lacc0[e] += v0;
        lacc1[e] += v1;
        Ps[wave][quad * 4 + e][pcol] = (__bf16)v0;
        Ps[wave][16 + quad * 4 + e][pcol] = (__bf16)v1;
      }
    }
    __builtin_amdgcn_wave_barrier();

    const int g4 = (l16 >> 2) << 4;  // reader's (row>>2)&3 swizzle term
#pragma unroll
    for (int kc = 0; kc < 2; kc++) {
      bf16x8 pf0 = *(const bf16x8*)&Ps[wave][l16][(kc * 32 + quad * 8) ^ g4];
      bf16x8 pf1 = *(const bf16x8*)&Ps[wave][16 + l16][(kc * 32 + quad * 8) ^ g4];
#pragma unroll
      for (int n = 0; n < 8; n++) {
        bf16x8 vf = *(const bf16x8*)&Vs[n * 16 + l16][kc * 32 + quad * 8];
        o0[n] = __builtin_amdgcn_mfma_f32_16x16x32_bf16(pf0, vf, o0[n], 0, 0, 0);
        o1[n] = __builtin_amdgcn_mfma_f32_16x16x32_bf16(pf1, vf, o1[n], 0, 0, 0);
      }
    }
    __builtin_amdgcn_wave_barrier();
  }

  // epilogue: reduce l across the 16 lanes of each quad, then Y = o / l
  const int hcol = (bh & 15) * 128;
  const size_t yrow0 = (size_t)b * T_ + qt * 128 + wave * 32 + quad * 4;
#pragma unroll
  for (int e = 0; e < 4; e++) {
    float l0 = lacc0[e], l1 = lacc1[e];
    l0 += __shfl_xor(l0, 1, 16); l1 += __shfl_xor(l1, 1, 16);
    l0 += __shfl_xor(l0, 2, 16); l1 += __shfl_xor(l1, 2, 16);
    l0 += __shfl_xor(l0, 4, 16); l1 += __shfl_xor(l1, 4, 16);
    l0 += __shfl_xor(l0, 8, 16); l1 += __shfl_xor(l1, 8, 16);
    float i0 = 1.f / l0, i1 = 1.f / l1;
#pragma unroll
    for (int n = 0; n < 8; n++) {
      Y[(yrow0 + e) * 2048 + hcol + n * 16 + l16] = (__bf16)(o0[n][e] * i0);
      Y[(yrow0 + 16 + e) * 2048 + hcol + n * 16 + l16] = (__bf16)(o1[n][e] * i1);
    }
  }
}

extern "C" void kernel_launch(void* const* d_in, const int* in_sizes, int n_in,
                              void* d_out, int out_size, void* d_ws, size_t ws_size,
                              hipStream_t stream) {
  const float* x = (const float*)d_in[0];
  const float* xall = (const float*)d_in[1];
  const int* posx = (const int*)d_in[2];
  const int* posxall = (const int*)d_in[3];
  const int* mask = (const int*)d_in[4];
  const float* Wq = (const float*)d_in[5];
  const float* Wk = (const float*)d_in[6];
  const float* Wv = (const float*)d_in[7];
  const float* Wo = (const float*)d_in[8];
  float* out = (float*)d_out;

  const size_t MB = 1024ull * 1024ull;
  if (ws_size < 192 * MB) return;
  char* ws = (char*)d_ws;
  __bf16* WqT   = (__bf16*)(ws + 0 * MB);     // 8 MiB each
  __bf16* WkT   = (__bf16*)(ws + 8 * MB);
  __bf16* WvT   = (__bf16*)(ws + 16 * MB);
  __bf16* WoT   = (__bf16*)(ws + 24 * MB);
  __bf16* xb    = (__bf16*)(ws + 32 * MB);    // 32 MiB each
  __bf16* xallb = (__bf16*)(ws + 64 * MB);
  __bf16* Qraw  = (__bf16*)(ws + 96 * MB);
  __bf16* Kraw  = (__bf16*)(ws + 128 * MB);
  __bf16* Vraw  = (__bf16*)(ws + 160 * MB);
  __bf16* Qr    = xb;                          // reuse after projections
  __bf16* Kr    = xallb;
  __bf16* Vtp   = Qraw;                        // reuse after rope(Q)
  __bf16* Y     = Kraw;                        // reuse after rope(K)

  const float QSCALE = (float)(0.08838834764831843 * 1.4426950408889634);

  cvt_f32_bf16<<<8192, 256, 0, stream>>>(x, xb);
  cvt_f32_bf16<<<8192, 256, 0, stream>>>(xall, xallb);

  transpose_w<<<4096, 256, 0, stream>>>(Wq, WqT);
  transpose_w<<<4096, 256, 0, stream>>>(Wk, WkT);
  transpose_w<<<4096, 256, 0, stream>>>(Wv, WvT);
  transpose_w<<<4096, 256, 0, stream>>>(Wo, WoT);

  // 256x256-tile 8-phase GEMMs: grid = (8192/256)*(2048/256) = 256 blocks
  gemm256<__bf16><<<256, 512, 0, stream>>>(xb, WqT, Qraw, 2048, 2048);
  gemm256<__bf16><<<256, 512, 0, stream>>>(xallb, WkT, Kraw, 2048, 2048);
  gemm256<__bf16><<<256, 512, 0, stream>>>(xallb, WvT, Vraw, 2048, 2048);

  rope_relayout<<<8192, 256, 0, stream>>>(Qraw, posx, Qr, QSCALE);
  rope_relayout<<<8192, 256, 0, stream>>>(Kraw, posxall, Kr, 1.0f);
  vtrans<<<16384, 256, 0, stream>>>(Vraw, Vtp);

  attn<<<1024, 256, 0, stream>>>(Qr, Kr, Vtp, mask, Y);

  gemm256<float><<<256, 512, 0, stream>>>(Y, WoT, out, 2048, 2048);
}

// Round 3
// 698.284 us; speedup vs baseline: 1.1785x; 1.1785x over previous
//
#include <hip/hip_runtime.h>

typedef __bf16 bf16x8 __attribute__((ext_vector_type(8)));
typedef float f32x4 __attribute__((ext_vector_type(4)));

#define B_ 4
#define H_ 16
#define T_ 2048
#define E_ 2048
#define D_ 128

// async global->LDS, 16B per lane; dest = wave-uniform base + lane*16
#define GLDS(g, l)                                                   \
  __builtin_amdgcn_global_load_lds(                                  \
      (const __attribute__((address_space(1))) void*)(g),            \
      (__attribute__((address_space(3))) void*)(l), 16, 0, 0)

// raw barrier: rendezvous only, no implicit vmcnt/lgkm drain
#define BAR() __builtin_amdgcn_s_barrier()

#define MFMA16(a, b, c) __builtin_amdgcn_mfma_f32_16x16x32_bf16((a), (b), (c), 0, 0, 0)

// ---------------- f32 -> bf16 elementwise convert ---------------------------
__global__ __launch_bounds__(256) void cvt_f32_bf16(const float* __restrict__ in,
                                                    __bf16* __restrict__ out) {
  size_t i = ((size_t)blockIdx.x * 256 + threadIdx.x) * 8;
  float4 a = *(const float4*)(in + i);
  float4 b = *(const float4*)(in + i + 4);
  bf16x8 v;
  v[0] = (__bf16)a.x; v[1] = (__bf16)a.y; v[2] = (__bf16)a.z; v[3] = (__bf16)a.w;
  v[4] = (__bf16)b.x; v[5] = (__bf16)b.y; v[6] = (__bf16)b.z; v[7] = (__bf16)b.w;
  *(bf16x8*)(out + i) = v;
}

// ------- 2048x2048 transpose + f32->bf16 (for weight B^T layout) ------------
__global__ __launch_bounds__(256) void transpose_w(const float* __restrict__ W,
                                                   __bf16* __restrict__ Wt) {
  __shared__ float tile[32][33];
  int bx = blockIdx.x & 63, by = blockIdx.x >> 6;
  int tx = threadIdx.x & 31, ty = threadIdx.x >> 5;
#pragma unroll
  for (int i = 0; i < 4; i++)
    tile[ty + i * 8][tx] = W[(size_t)(by * 32 + ty + i * 8) * 2048 + bx * 32 + tx];
  __syncthreads();
#pragma unroll
  for (int i = 0; i < 4; i++)
    Wt[(size_t)(bx * 32 + ty + i * 8) * 2048 + by * 32 + tx] =
        (__bf16)tile[tx][ty + i * 8];
}

// ---- bf16 GEMM: C[M,N] = A[M,K] @ Bt[N,K]^T ------------------------------
// 256x256 tile, BK=64, 8 waves (2M x 4N), 4 SEPARATE 32 KiB LDS buffers
// (As0/As1/Bs0/Bs1) with COMPILE-TIME buffer selection (K-loop unrolled x2).
// Rationale: with As[2][..] + runtime index, SIInsertWaitcnts cannot
// disambiguate in-flight global_load_lds (to buf d^1) from ds_reads (of buf
// d) and inserts ~vmcnt(0) drains before every read phase — measured as the
// 8-phase schedule giving 0 gain in rounds 0-2.  Distinct objects let alias
// analysis separate them; only the counted vmcnt(6) remains.
// Stage lead per K-tile T (4 phases): ph0 stages A-next h1 (T+1), ph2 stages
// B-cur h0 (T+2), ph3 stages A-cur h0 + B-cur h1 (T+2).  vmcnt(6) at end of
// ph3 leaves exactly the 3 newest half-tiles (T+2) in flight; all of T+1
// resident.  LDS: [256][64] bf16 per buffer, 16B-chunk XOR swizzle
// phys = logical ^ (row&7), pre-swizzled GLDS source -> conflict-free b128.
template <typename TOut>
__global__ __launch_bounds__(512, 2)
void gemm256(const __bf16* __restrict__ A, const __bf16* __restrict__ Bt,
             TOut* __restrict__ C, int N, int K) {
  __shared__ alignas(16) __bf16 As0[256 * 64];
  __shared__ alignas(16) __bf16 As1[256 * 64];
  __shared__ alignas(16) __bf16 Bs0[256 * 64];
  __shared__ alignas(16) __bf16 Bs1[256 * 64];

  // XCD-aware bijective swizzle (gridDim multiple of 8)
  const int nwg = gridDim.x;
  const int wg = (blockIdx.x & 7) * (nwg >> 3) + (blockIdx.x >> 3);
  const int ntn = N >> 8;
  const int tm = wg / ntn, tn = wg % ntn;

  const int tid = threadIdx.x;
  const int wave = tid >> 6, lane = tid & 63;
  const int quad = lane >> 4, l16 = lane & 15;
  const int wm = wave >> 2, wn = wave & 3;

  // staging source (pre-swizzled chunk so linear GLDS dest == swizzled layout)
  const int srow = wave * 8 + (lane >> 3);
  const int scol = (((lane & 7) ^ ((lane >> 3) & 7)) << 3);
  const __bf16* gA = A + (size_t)(tm * 256 + srow) * K + scol;
  const __bf16* gB = Bt + (size_t)(tn * 256 + srow) * K + scol;
  const int sdst = wave * 512;  // wave*8 rows * 64 bf16

// stage one 128-row half (h) of k-tile U into array ARR (A source)
#define STAGE_A_TO(ARR, h, U)                                                  \
  do {                                                                         \
    GLDS(gA + (size_t)((h)*128) * K + (size_t)(U)*64, &ARR[(h)*8192 + sdst]);  \
    GLDS(gA + (size_t)((h)*128 + 64) * K + (size_t)(U)*64,                     \
         &ARR[(h)*8192 + 4096 + sdst]);                                        \
  } while (0)
#define STAGE_B_TO(ARR, h, U)                                                  \
  do {                                                                         \
    GLDS(gB + (size_t)((h)*128) * K + (size_t)(U)*64, &ARR[(h)*8192 + sdst]);  \
    GLDS(gB + (size_t)((h)*128 + 64) * K + (size_t)(U)*64,                     \
         &ARR[(h)*8192 + 4096 + sdst]);                                        \
  } while (0)

  const int NT = K >> 6;  // K-tiles of 64; NT even (K=2048 -> 32)

  // frag chunk offsets (bf16 units): chunk(ks) = ((ks<<2)|quad) ^ (row&7)
  const int c0 = ((quad ^ (l16 & 7)) << 3);
  const int c1 = (((quad ^ (l16 & 7)) ^ 4) << 3);

  const f32x4 z4 = {0.f, 0.f, 0.f, 0.f};
  f32x4 acc[8][4];
#pragma unroll
  for (int m = 0; m < 8; m++)
#pragma unroll
    for (int n = 0; n < 4; n++) acc[m][n] = z4;

  bf16x8 a[4][2], b[4][2];

  // -------- prologue: K-tile 0 (buf0) + 3 newest half-tiles of K-tile 1 ----
  STAGE_A_TO(As0, 0, 0);
  STAGE_B_TO(Bs0, 0, 0);
  STAGE_B_TO(Bs0, 1, 0);
  STAGE_A_TO(As0, 1, 0);
  STAGE_B_TO(Bs1, 0, 1);
  STAGE_A_TO(As1, 0, 1);
  STAGE_B_TO(Bs1, 1, 1);
  asm volatile("s_waitcnt vmcnt(6)");  // K-tile 0 resident (counted)
  BAR();

// One K-tile: reads from (AC,BC); stages A-next h1 (Tc+1) into AN,
// B-cur h0 + A-cur h0 + B-cur h1 (Tc+2) into BC/AC.
#define KTILE(AC, BC, AN, Tc)                                                  \
  {                                                                            \
    const bool s1 = ((Tc) + 1 < NT), s2 = ((Tc) + 2 < NT);                     \
    /* ---- phase 0: read A m0-3 + B n0-1; stage AN h1 (Tc+1) */               \
    _Pragma("unroll") for (int m = 0; m < 4; m++) {                            \
      const __bf16* p = &AC[(wm * 128 + m * 16 + l16) * 64];                   \
      a[m][0] = *(const bf16x8*)(p + c0);                                      \
      a[m][1] = *(const bf16x8*)(p + c1);                                      \
    }                                                                          \
    _Pragma("unroll") for (int n = 0; n < 2; n++) {                            \
      const __bf16* p = &BC[(wn * 64 + n * 16 + l16) * 64];                    \
      b[n][0] = *(const bf16x8*)(p + c0);                                      \
      b[n][1] = *(const bf16x8*)(p + c1);                                      \
    }                                                                          \
    if (s1) STAGE_A_TO(AN, 1, (Tc) + 1);                                       \
    BAR();                                                                     \
    asm volatile("s_waitcnt lgkmcnt(0)");                                      \
    __builtin_amdgcn_s_setprio(1);                                             \
    _Pragma("unroll") for (int m = 0; m < 4; m++)                              \
        _Pragma("unroll") for (int n = 0; n < 2; n++) {                        \
      acc[m][n] = MFMA16(a[m][0], b[n][0], acc[m][n]);                         \
      acc[m][n] = MFMA16(a[m][1], b[n][1], acc[m][n]);                         \
    }                                                                          \
    __builtin_amdgcn_s_setprio(0);                                             \
    BAR();                                                                     \
    /* ---- phase 1: read B n2-3 */                                            \
    _Pragma("unroll") for (int n = 2; n < 4; n++) {                            \
      const __bf16* p = &BC[(wn * 64 + n * 16 + l16) * 64];                    \
      b[n][0] = *(const bf16x8*)(p + c0);                                      \
      b[n][1] = *(const bf16x8*)(p + c1);                                      \
    }                                                                          \
    BAR();                                                                     \
    asm volatile("s_waitcnt lgkmcnt(0)");                                      \
    __builtin_amdgcn_s_setprio(1);                                             \
    _Pragma("unroll") for (int m = 0; m < 4; m++)                              \
        _Pragma("unroll") for (int n = 2; n < 4; n++) {                        \
      acc[m][n] = MFMA16(a[m][0], b[n][0], acc[m][n]);                         \
      acc[m][n] = MFMA16(a[m][1], b[n][1], acc[m][n]);                         \
    }                                                                          \
    __builtin_amdgcn_s_setprio(0);                                             \
    BAR();                                                                     \
    /* ---- phase 2: read A m4-7; stage BC h0 (Tc+2) */                        \
    _Pragma("unroll") for (int m = 0; m < 4; m++) {                            \
      const __bf16* p = &AC[(wm * 128 + (m + 4) * 16 + l16) * 64];             \
      a[m][0] = *(const bf16x8*)(p + c0);                                      \
      a[m][1] = *(const bf16x8*)(p + c1);                                      \
    }                                                                          \
    if (s2) STAGE_B_TO(BC, 0, (Tc) + 2);                                       \
    BAR();                                                                     \
    asm volatile("s_waitcnt lgkmcnt(0)");                                      \
    __builtin_amdgcn_s_setprio(1);                                             \
    _Pragma("unroll") for (int m = 0; m < 4; m++)                              \
        _Pragma("unroll") for (int n = 2; n < 4; n++) {                        \
      acc[m + 4][n] = MFMA16(a[m][0], b[n][0], acc[m + 4][n]);                 \
      acc[m + 4][n] = MFMA16(a[m][1], b[n][1], acc[m + 4][n]);                 \
    }                                                                          \
    __builtin_amdgcn_s_setprio(0);                                             \
    BAR();                                                                     \
    /* ---- phase 3: no reads; stage AC h0 + BC h1 (Tc+2) */                   \
    if (s2) {                                                                  \
      STAGE_A_TO(AC, 0, (Tc) + 2);                                             \
      STAGE_B_TO(BC, 1, (Tc) + 2);                                             \
    }                                                                          \
    BAR();                                                                     \
    __builtin_amdgcn_s_setprio(1);                                             \
    _Pragma("unroll") for (int m = 0; m < 4; m++)                              \
        _Pragma("unroll") for (int n = 0; n < 2; n++) {                        \
      acc[m + 4][n] = MFMA16(a[m][0], b[n][0], acc[m + 4][n]);                 \
      acc[m + 4][n] = MFMA16(a[m][1], b[n][1], acc[m + 4][n]);                 \
    }                                                                          \
    __builtin_amdgcn_s_setprio(0);                                             \
    if (s2)                                                                    \
      asm volatile("s_waitcnt vmcnt(6)");                                      \
    else                                                                       \
      asm volatile("s_waitcnt vmcnt(0)");                                      \
    BAR();                                                                     \
  }

  for (int Tc = 0; Tc < NT; Tc += 2) {
    KTILE(As0, Bs0, As1, Tc);
    KTILE(As1, Bs1, As0, Tc + 1);
  }
#undef KTILE
#undef STAGE_A_TO
#undef STAGE_B_TO

  // -------- epilogue: C[16x16 frag layout col=l16, row=quad*4+e] ----------
  const size_t rbase = (size_t)tm * 256 + wm * 128 + quad * 4;
  const int cbase = tn * 256 + wn * 64 + l16;
#pragma unroll
  for (int m = 0; m < 8; m++)
#pragma unroll
    for (int n = 0; n < 4; n++)
#pragma unroll
      for (int e = 0; e < 4; e++)
        C[(rbase + m * 16 + e) * N + cbase + n * 16] = (TOut)acc[m][n][e];
}

// ------------- RoPE + relayout [B*T, H*D] -> [B,H,T,D] ----------------------
// `scale` folds 1/sqrt(D)*log2(e) into Q so QK^T lands in the exp2 domain.
__global__ __launch_bounds__(256) void rope_relayout(const __bf16* __restrict__ raw,
                                                     const int* __restrict__ pos,
                                                     __bf16* __restrict__ out,
                                                     float scale) {
  int row = blockIdx.x;  // b*T + t
  int b = row >> 11, t = row & 2047;
  float p = (float)pos[row];
  for (int i = threadIdx.x; i < 1024; i += 256) {
    int h = i >> 6, d = i & 63;
    float inv = exp2f((float)d * -0.2076205059304601f);
    float ang = p * inv;
    float c = cosf(ang) * scale, s = sinf(ang) * scale;
    float q1 = (float)raw[(size_t)row * 2048 + h * 128 + d];
    float q2 = (float)raw[(size_t)row * 2048 + h * 128 + d + 64];
    size_t o = ((size_t)(b * 16 + h) * 2048 + t) * 128 + d;
    out[o] = (__bf16)(q1 * c - q2 * s);
    out[o + 64] = (__bf16)(q2 * c + q1 * s);
  }
}

// ------------- V relayout [B*T, H*D] -> Vt [B,H,D,T] ------------------------
__global__ __launch_bounds__(256) void vtrans(const __bf16* __restrict__ Vraw,
                                              __bf16* __restrict__ Vt) {
  __shared__ __bf16 tile[32][33];
  int dt = blockIdx.x & 3, tt = (blockIdx.x >> 2) & 63, bh = blockIdx.x >> 8;
  int b = bh >> 4, h = bh & 15;
  int tx = threadIdx.x & 31, ty = threadIdx.x >> 5;
#pragma unroll
  for (int i = 0; i < 4; i++) {
    int t = tt * 32 + ty + i * 8;
    tile[ty + i * 8][tx] = Vraw[(size_t)(b * T_ + t) * 2048 + h * 128 + dt * 32 + tx];
  }
  __syncthreads();
#pragma unroll
  for (int i = 0; i < 4; i++) {
    int d = dt * 32 + ty + i * 8;
    Vt[((size_t)bh * 128 + d) * T_ + tt * 32 + tx] = tile[tx][ty + i * 8];
  }
}

// ---- flash attention: 128 q/block, 32 q/wave (2 subtiles), 64-key tiles ----
__global__ __launch_bounds__(256, 2)
void attn(const __bf16* __restrict__ Q, const __bf16* __restrict__ K,
          const __bf16* __restrict__ Vt, const int* __restrict__ mask,
          __bf16* __restrict__ Y) {
  __shared__ alignas(16) __bf16 Ks[64][136];   // [key][d], +8 pad
  __shared__ alignas(16) __bf16 Vs[128][72];   // [d][key], +8 pad
  __shared__ alignas(16) __bf16 Ps[4][32][64]; // per-wave P, XOR-16 swizzled cols

  const int qt = blockIdx.x & 15;  // T_/128 q-tiles
  const int bh = blockIdx.x >> 4;
  const int b = bh >> 4;
  const __bf16* Qb = Q + (size_t)bh * T_ * 128;
  const __bf16* Kb = K + (size_t)bh * T_ * 128;
  const __bf16* Vb = Vt + (size_t)bh * 128 * T_;
  const int* mb = mask + (size_t)b * T_;

  const int tid = threadIdx.x, wave = tid >> 6, lane = tid & 63;
  const int quad = lane >> 4, l16 = lane & 15;

  // Q fragments for 2 q-subtiles: A-layout A[m=l16][k=quad*8+j]
  bf16x8 qf[2][4];
  {
    int qrow = qt * 128 + wave * 32 + l16;
#pragma unroll
    for (int sub = 0; sub < 2; sub++)
#pragma unroll
      for (int kc = 0; kc < 4; kc++)
        qf[sub][kc] =
            *(const bf16x8*)(Qb + (size_t)(qrow + sub * 16) * 128 + kc * 32 + quad * 8);
  }

  const f32x4 z4 = {0.f, 0.f, 0.f, 0.f};
  f32x4 o0[8], o1[8];
#pragma unroll
  for (int n = 0; n < 8; n++) { o0[n] = z4; o1[n] = z4; }
  float lacc0[4] = {0.f, 0.f, 0.f, 0.f};
  float lacc1[4] = {0.f, 0.f, 0.f, 0.f};

  for (int t0 = 0; t0 < T_; t0 += 64) {
    __syncthreads();
#pragma unroll
    for (int rr = 0; rr < 4; rr++) {
      int idx = rr * 256 + tid;
      *(uint4*)&Ks[idx >> 4][(idx & 15) << 3] =
          *(const uint4*)(Kb + (size_t)(t0 + (idx >> 4)) * 128 + ((idx & 15) << 3));
      *(uint4*)&Vs[idx >> 3][(idx & 7) << 3] =
          *(const uint4*)(Vb + (size_t)(idx >> 3) * T_ + t0 + ((idx & 7) << 3));
    }
    __syncthreads();

    // S = Q K^T for both q-subtiles, sharing every kf read (exp2 domain)
    f32x4 s0[4], s1[4];
#pragma unroll
    for (int c = 0; c < 4; c++) { s0[c] = z4; s1[c] = z4; }
#pragma unroll
    for (int c = 0; c < 4; c++)
#pragma unroll
      for (int kc = 0; kc < 4; kc++) {
        bf16x8 kf = *(const bf16x8*)&Ks[c * 16 + l16][kc * 32 + quad * 8];
        s0[c] = __builtin_amdgcn_mfma_f32_16x16x32_bf16(qf[0][kc], kf, s0[c], 0, 0, 0);
        s1[c] = __builtin_amdgcn_mfma_f32_16x16x32_bf16(qf[1][kc], kf, s1[c], 0, 0, 0);
      }

    int mk[4];
#pragma unroll
    for (int c = 0; c < 4; c++) mk[c] = mb[t0 + c * 16 + l16];

#pragma unroll
    for (int c = 0; c < 4; c++) {
      int pcol = (c * 16 + l16) ^ (quad << 4);  // swizzle keyed on (row>>2)&3==quad
#pragma unroll
      for (int e = 0; e < 4; e++) {
        float v0 = __builtin_amdgcn_exp2f(s0[c][e]);
        float v1 = __builtin_amdgcn_exp2f(s1[c][e]);
        v0 = mk[c] ? 0.f : v0;   // exact: ref exp(finfo.min - m) == 0
        v1 = mk[c] ? 0.f : v1;
        lacc0[e] += v0;
        lacc1[e] += v1;
        Ps[wave][quad * 4 + e][pcol] = (__bf16)v0;
        Ps[wave][16 + quad * 4 + e][pcol] = (__bf16)v1;
      }
    }
    __builtin_amdgcn_wave_barrier();

    const int g4 = (l16 >> 2) << 4;  // reader's (row>>2)&3 swizzle term
#pragma unroll
    for (int kc = 0; kc < 2; kc++) {
      bf16x8 pf0 = *(const bf16x8*)&Ps[wave][l16][(kc * 32 + quad * 8) ^ g4];
      bf16x8 pf1 = *(const bf16x8*)&Ps[wave][16 + l16][(kc * 32 + quad * 8) ^ g4];
#pragma unroll
      for (int n = 0; n < 8; n++) {
        bf16x8 vf = *(const bf16x8*)&Vs[n * 16 + l16][kc * 32 + quad * 8];
        o0[n] = __builtin_amdgcn_mfma_f32_16x16x32_bf16(pf0, vf, o0[n], 0, 0, 0);
        o1[n] = __builtin_amdgcn_mfma_f32_16x16x32_bf16(pf1, vf, o1[n], 0, 0, 0);
      }
    }
    __builtin_amdgcn_wave_barrier();
  }

  // epilogue: reduce l across the 16 lanes of each quad, then Y = o / l
  const int hcol = (bh & 15) * 128;
  const size_t yrow0 = (size_t)b * T_ + qt * 128 + wave * 32 + quad * 4;
#pragma unroll
  for (int e = 0; e < 4; e++) {
    float l0 = lacc0[e], l1 = lacc1[e];
    l0 += __shfl_xor(l0, 1, 16); l1 += __shfl_xor(l1, 1, 16);
    l0 += __shfl_xor(l0, 2, 16); l1 += __shfl_xor(l1, 2, 16);
    l0 += __shfl_xor(l0, 4, 16); l1 += __shfl_xor(l1, 4, 16);
    l0 += __shfl_xor(l0, 8, 16); l1 += __shfl_xor(l1, 8, 16);
    float i0 = 1.f / l0, i1 = 1.f / l1;
#pragma unroll
    for (int n = 0; n < 8; n++) {
      Y[(yrow0 + e) * 2048 + hcol + n * 16 + l16] = (__bf16)(o0[n][e] * i0);
      Y[(yrow0 + 16 + e) * 2048 + hcol + n * 16 + l16] = (__bf16)(o1[n][e] * i1);
    }
  }
}

extern "C" void kernel_launch(void* const* d_in, const int* in_sizes, int n_in,
                              void* d_out, int out_size, void* d_ws, size_t ws_size,
                              hipStream_t stream) {
  const float* x = (const float*)d_in[0];
  const float* xall = (const float*)d_in[1];
  const int* posx = (const int*)d_in[2];
  const int* posxall = (const int*)d_in[3];
  const int* mask = (const int*)d_in[4];
  const float* Wq = (const float*)d_in[5];
  const float* Wk = (const float*)d_in[6];
  const float* Wv = (const float*)d_in[7];
  const float* Wo = (const float*)d_in[8];
  float* out = (float*)d_out;

  const size_t MB = 1024ull * 1024ull;
  if (ws_size < 192 * MB) return;
  char* ws = (char*)d_ws;
  __bf16* WqT   = (__bf16*)(ws + 0 * MB);     // 8 MiB each
  __bf16* WkT   = (__bf16*)(ws + 8 * MB);
  __bf16* WvT   = (__bf16*)(ws + 16 * MB);
  __bf16* WoT   = (__bf16*)(ws + 24 * MB);
  __bf16* xb    = (__bf16*)(ws + 32 * MB);    // 32 MiB each
  __bf16* xallb = (__bf16*)(ws + 64 * MB);
  __bf16* Qraw  = (__bf16*)(ws + 96 * MB);
  __bf16* Kraw  = (__bf16*)(ws + 128 * MB);
  __bf16* Vraw  = (__bf16*)(ws + 160 * MB);
  __bf16* Qr    = xb;                          // reuse after projections
  __bf16* Kr    = xallb;
  __bf16* Vtp   = Qraw;                        // reuse after rope(Q)
  __bf16* Y     = Kraw;                        // reuse after rope(K)

  const float QSCALE = (float)(0.08838834764831843 * 1.4426950408889634);

  cvt_f32_bf16<<<8192, 256, 0, stream>>>(x, xb);
  cvt_f32_bf16<<<8192, 256, 0, stream>>>(xall, xallb);

  transpose_w<<<4096, 256, 0, stream>>>(Wq, WqT);
  transpose_w<<<4096, 256, 0, stream>>>(Wk, WkT);
  transpose_w<<<4096, 256, 0, stream>>>(Wv, WvT);
  transpose_w<<<4096, 256, 0, stream>>>(Wo, WoT);

  // 256x256-tile 8-phase GEMMs: grid = (8192/256)*(2048/256) = 256 blocks
  gemm256<__bf16><<<256, 512, 0, stream>>>(xb, WqT, Qraw, 2048, 2048);
  gemm256<__bf16><<<256, 512, 0, stream>>>(xallb, WkT, Kraw, 2048, 2048);
  gemm256<__bf16><<<256, 512, 0, stream>>>(xallb, WvT, Vraw, 2048, 2048);

  rope_relayout<<<8192, 256, 0, stream>>>(Qraw, posx, Qr, QSCALE);
  rope_relayout<<<8192, 256, 0, stream>>>(Kraw, posxall, Kr, 1.0f);
  vtrans<<<16384, 256, 0, stream>>>(Vraw, Vtp);

  attn<<<1024, 256, 0, stream>>>(Qr, Kr, Vtp, mask, Y);

  gemm256<float><<<256, 512, 0, stream>>>(Y, WoT, out, 2048, 2048);
}